// Round 4
// baseline (2980.968 us; speedup 1.0000x reference)
//
#include <hip/hip_runtime.h>

#define T_STEPS 512
#define BATCH   256

typedef _Float16 f16;
typedef __attribute__((ext_vector_type(8))) _Float16 f16x8;
typedef __attribute__((ext_vector_type(4))) _Float16 f16x4;
typedef __attribute__((ext_vector_type(4))) float    f32x4;

__device__ __forceinline__ float sigmoid_f(float x) {
    return 1.0f / (1.0f + __expf(-x));
}
__device__ __forceinline__ float tanh_f(float x) {
    return 1.0f - 2.0f / (__expf(2.0f * x) + 1.0f);
}

// LDS-only barrier: __syncthreads() drains vmcnt(0) (global loads AND stores),
// putting store-retire latency on the per-step critical path. We only need LDS
// visibility at the step boundary.
__device__ __forceinline__ void barrier_lds_only() {
    asm volatile("s_waitcnt lgkmcnt(0)\n\ts_barrier" ::: "memory");
}

// One block per 16 batch elements (grid=16). Wave w owns units [16w,16w+16) of
// all four gates: 4 C-tiles (16x16) per step via mfma_f32_16x16x32_f16 over
// K = IN_DIM + H. Weights = step-invariant B-frags in registers. x_t / h in
// double-buffered f16 LDS; one LDS-only barrier per step.
// Step order: prefetch-loads -> ds_read A -> MFMA -> LDS commit (vmcnt wait
// covers only the loads) -> gates -> h write -> out stores (drain off-path).
// All per-step addresses are pointer+stride increments (no 64-bit muls in loop).
template <int IN_DIM, int H, bool IN_F16, bool OUT_F16, bool APPLY_TANH>
__global__ __launch_bounds__(4 * H, 1)
void lstm_mfma(const void* __restrict__ xv,
               const float* __restrict__ w_ih,   // [4H, IN_DIM]
               const float* __restrict__ w_hh,   // [4H, H]
               const float* __restrict__ b_ih,   // [4H]
               const float* __restrict__ b_hh,   // [4H]
               void* __restrict__ outv)          // [T, B, H] (f16 or f32)
{
    constexpr int KTX = IN_DIM / 32;
    constexpr int KTH = H / 32;
    constexpr int KT  = KTX + KTH;
    constexpr int XP  = IN_DIM + 8;     // rows 16B-aligned, stride 144B-class
    constexpr int HP  = H + 8;
    constexpr int NT  = 4 * H;
    constexpr int ELD = IN_F16 ? 8 : 4;           // input elements per 16B chunk
    constexpr int NCH = 16 * IN_DIM / ELD;        // chunks per timestep panel
    constexpr int CPT = (NCH + NT - 1) / NT;      // chunks per thread (1 or 2)
    constexpr int EPR = IN_DIM / ELD;             // chunks per row

    __shared__ f16 xs[2][16][XP];
    __shared__ f16 hs[2][16][HP];

    const int tid  = threadIdx.x;
    const int wave = tid >> 6;
    const int lane = tid & 63;
    const int col  = lane & 15;
    const int q    = lane >> 4;
    const int bblk = blockIdx.x * 16;
    const int u    = wave * 16 + col;

    // ---- one-time: B-fragments (weights) -> registers ----
    // lane supplies B[k = kt*32 + q*8 + j][n = col]; W rows [n][k] row-major.
    f16x8 bw[4][KT];
#pragma unroll
    for (int g = 0; g < 4; ++g) {
        const int row = g * H + u;
#pragma unroll
        for (int kt = 0; kt < KTX; ++kt) {
            const float* p = w_ih + (size_t)row * IN_DIM + kt * 32 + q * 8;
            f16x8 v;
#pragma unroll
            for (int j = 0; j < 8; ++j) v[j] = (f16)p[j];
            bw[g][kt] = v;
        }
#pragma unroll
        for (int kt = 0; kt < KTH; ++kt) {
            const float* p = w_hh + (size_t)row * H + kt * 32 + q * 8;
            f16x8 v;
#pragma unroll
            for (int j = 0; j < 8; ++j) v[j] = (f16)p[j];
            bw[g][KTX + kt] = v;
        }
    }
    float bias[4];
#pragma unroll
    for (int g = 0; g < 4; ++g) bias[g] = b_ih[g * H + u] + b_hh[g * H + u];

    float cst[4] = {0.f, 0.f, 0.f, 0.f};

    // ---- per-thread staging setup (hoisted out of the loop) ----
    // chunk cc = tid + k*NT; row = cc/EPR, off = cc%EPR. Valid iff cc < NCH
    // (wave-uniform for our shapes). Global ptr advances by BATCH*IN_DIM elems.
    bool        sv[CPT];
    const void* sgp[CPT];              // global src pointer (advances per step)
    f16*        slp[CPT];              // LDS dst in buffer 0 (add delta for buf 1)
    const int   LDS_DELTA = 16 * XP;   // f16 elements between xs[0] and xs[1]
#pragma unroll
    for (int k = 0; k < CPT; ++k) {
        const int cc  = tid + k * NT;
        sv[k] = (cc < NCH);
        const int r_  = (cc < NCH ? cc : 0) / EPR;
        const int o_  = (cc < NCH ? cc : 0) % EPR;
        if constexpr (IN_F16)
            sgp[k] = (const f16*)xv + ((size_t)bblk + r_) * IN_DIM + o_ * ELD;
        else
            sgp[k] = (const float*)xv + ((size_t)bblk + r_) * IN_DIM + o_ * ELD;
        slp[k] = &xs[0][r_][o_ * ELD];
    }
    constexpr int XADV = BATCH * IN_DIM;   // elements per timestep

    // per-lane output pointer: row (bblk + 4q), col u; +r*H inside step
    void* outp;
    if constexpr (OUT_F16) outp = (f16*)outv   + ((size_t)bblk + 4 * q) * H + u;
    else                   outp = (float*)outv + ((size_t)bblk + 4 * q) * H + u;

    // ---- init: h(0) = 0, stage x(0) synchronously ----
    for (int i = tid; i < 16 * HP; i += NT) hs[0][i / HP][i % HP] = (f16)0.f;
#pragma unroll
    for (int k = 0; k < CPT; ++k) {
        if (sv[k]) {
            if constexpr (IN_F16) {
                *reinterpret_cast<f16x8*>(slp[k]) =
                    *reinterpret_cast<const f16x8*>((const f16*)sgp[k]);
            } else {
                const f32x4 v = *reinterpret_cast<const f32x4*>((const float*)sgp[k]);
                f16x4 h4;
                h4[0] = (f16)v[0]; h4[1] = (f16)v[1]; h4[2] = (f16)v[2]; h4[3] = (f16)v[3];
                *reinterpret_cast<f16x4*>(slp[k]) = h4;
            }
            sgp[k] = (const char*)sgp[k] + XADV * (IN_F16 ? 2 : 4);  // now points at t=1
        }
    }
    __syncthreads();

    int pb = 0;
    for (int t = 0; t < T_STEPS; ++t) {
        // ---- 1. issue x(t+1) prefetch loads ----
        f16x8 xr16[CPT];
        f32x4 xr32[CPT];
        const bool pf = (t + 1 < T_STEPS);
        if (pf) {
#pragma unroll
            for (int k = 0; k < CPT; ++k) {
                if (sv[k]) {
                    if constexpr (IN_F16)
                        xr16[k] = *reinterpret_cast<const f16x8*>((const f16*)sgp[k]);
                    else
                        xr32[k] = *reinterpret_cast<const f32x4*>((const float*)sgp[k]);
                    sgp[k] = (const char*)sgp[k] + XADV * (IN_F16 ? 2 : 4);
                }
            }
        }

        // ---- 2. A-fragments from LDS ----
        f16x8 a[KT];
#pragma unroll
        for (int kt = 0; kt < KTX; ++kt)
            a[kt] = *reinterpret_cast<const f16x8*>(&xs[pb][col][kt * 32 + q * 8]);
#pragma unroll
        for (int kt = 0; kt < KTH; ++kt)
            a[KTX + kt] = *reinterpret_cast<const f16x8*>(&hs[pb][col][kt * 32 + q * 8]);

        // ---- 3. MFMA: 4 gate accumulators ----
        f32x4 acc[4];
#pragma unroll
        for (int g = 0; g < 4; ++g)
            acc[g] = (f32x4){bias[g], bias[g], bias[g], bias[g]};
#pragma unroll
        for (int kt = 0; kt < KT; ++kt)
#pragma unroll
            for (int g = 0; g < 4; ++g)
                acc[g] = __builtin_amdgcn_mfma_f32_16x16x32_f16(a[kt], bw[g][kt], acc[g], 0, 0, 0);

        // ---- 4. commit x(t+1) to LDS (vmcnt wait covers only the loads) ----
        if (pf) {
#pragma unroll
            for (int k = 0; k < CPT; ++k) {
                if (sv[k]) {
                    f16* dst = slp[k] + (pb ^ 1) * LDS_DELTA;
                    if constexpr (IN_F16) {
                        *reinterpret_cast<f16x8*>(dst) = xr16[k];
                    } else {
                        f16x4 h4;
                        h4[0] = (f16)xr32[k][0]; h4[1] = (f16)xr32[k][1];
                        h4[2] = (f16)xr32[k][2]; h4[3] = (f16)xr32[k][3];
                        *reinterpret_cast<f16x4*>(dst) = h4;
                    }
                }
            }
        }

        // ---- 5. gates -> c,h; h to LDS; out stores last (drain off-path) ----
        float hv[4];
#pragma unroll
        for (int r = 0; r < 4; ++r) {
            const float gi = acc[0][r];
            const float gf = acc[1][r];
            const float gg = acc[2][r];
            const float go = acc[3][r];
            cst[r] = sigmoid_f(gf) * cst[r] + sigmoid_f(gi) * tanh_f(gg);
            const float h = sigmoid_f(go) * tanh_f(cst[r]);
            hv[r] = h;
            hs[pb ^ 1][4 * q + r][u] = (f16)h;
        }
#pragma unroll
        for (int r = 0; r < 4; ++r) {
            const float ov = APPLY_TANH ? tanh_f(hv[r]) : hv[r];
            if constexpr (OUT_F16) ((f16*)outp)[r * H]   = (f16)ov;
            else                   ((float*)outp)[r * H] = ov;
        }
        if constexpr (OUT_F16) outp = (f16*)outp   + (size_t)BATCH * H;
        else                   outp = (float*)outp + (size_t)BATCH * H;

        barrier_lds_only();
        pb ^= 1;
    }
}

extern "C" void kernel_launch(void* const* d_in, const int* in_sizes, int n_in,
                              void* d_out, int out_size, void* d_ws, size_t ws_size,
                              hipStream_t stream) {
    const float* X     = (const float*)d_in[0];
    const float* w1_ih = (const float*)d_in[1];
    const float* w1_hh = (const float*)d_in[2];
    const float* b1_ih = (const float*)d_in[3];
    const float* b1_hh = (const float*)d_in[4];
    const float* w2_ih = (const float*)d_in[5];
    const float* w2_hh = (const float*)d_in[6];
    const float* b2_ih = (const float*)d_in[7];
    const float* b2_hh = (const float*)d_in[8];
    const float* w3_ih = (const float*)d_in[9];
    const float* w3_hh = (const float*)d_in[10];
    const float* b3_ih = (const float*)d_in[11];
    const float* b3_hh = (const float*)d_in[12];
    const float* w4_ih = (const float*)d_in[13];
    const float* w4_hh = (const float*)d_in[14];
    const float* b4_ih = (const float*)d_in[15];
    const float* b4_hh = (const float*)d_in[16];

    float* out = (float*)d_out;

    // inter-layer staging in f16 (same values as the recurrence panels — no
    // extra rounding): h1 [512,256,128], h2 [512,256,32], h3 [512,256,128]
    f16* h1 = (f16*)d_ws;
    f16* h2 = h1 + (size_t)T_STEPS * BATCH * 128;
    f16* h3 = h2 + (size_t)T_STEPS * BATCH * 32;

    constexpr int GRID = BATCH / 16;

    lstm_mfma<64, 128, false, true, false><<<GRID, 512, 0, stream>>>(
        X, w1_ih, w1_hh, b1_ih, b1_hh, h1);
    lstm_mfma<128, 32, true, true, true><<<GRID, 128, 0, stream>>>(
        h1, w2_ih, w2_hh, b2_ih, b2_hh, h2);
    lstm_mfma<32, 128, true, true, false><<<GRID, 512, 0, stream>>>(
        h2, w3_ih, w3_hh, b3_ih, b3_hh, h3);
    lstm_mfma<128, 64, true, false, false><<<GRID, 256, 0, stream>>>(
        h3, w4_ih, w4_hh, b4_ih, b4_hh, out);
}

// Round 5
// 1036.803 us; speedup vs baseline: 2.8752x; 2.8752x over previous
//
#include <hip/hip_runtime.h>

#define T_STEPS 512
#define BATCH   256

typedef _Float16 f16;
typedef unsigned long long u64;
typedef __attribute__((ext_vector_type(8))) _Float16 f16x8;
typedef __attribute__((ext_vector_type(4))) _Float16 f16x4;
typedef __attribute__((ext_vector_type(4))) float    f32x4;

__device__ __forceinline__ float rcp_f(float x) { return __builtin_amdgcn_rcpf(x); }
__device__ __forceinline__ float sigmoid_f(float x) { return rcp_f(1.0f + __expf(-x)); }
__device__ __forceinline__ float tanh_f(float x) {
    return 1.0f - 2.0f * rcp_f(__expf(2.0f * x) + 1.0f);
}

// Full-drain barrier: vm drain needed so the producer flag protocol can rely
// on "stores issued before the previous barrier are globally visible".
__device__ __forceinline__ void barrier_step() {
    asm volatile("s_waitcnt vmcnt(0) lgkmcnt(0)\n\ts_barrier" ::: "memory");
}

// Agent-scope relaxed atomics -> sc1 ops, coherent across XCDs at the
// Infinity-Cache level; no cache-wide writeback/invalidate instructions.
__device__ __forceinline__ int  flag_load(const int* p) {
    return __hip_atomic_load(p, __ATOMIC_RELAXED, __HIP_MEMORY_SCOPE_AGENT);
}
__device__ __forceinline__ void flag_store(int* p, int v) {
    __hip_atomic_store(p, v, __ATOMIC_RELAXED, __HIP_MEMORY_SCOPE_AGENT);
}
__device__ __forceinline__ u64  panel_load(const u64* p) {
    return __hip_atomic_load(p, __ATOMIC_RELAXED, __HIP_MEMORY_SCOPE_AGENT);
}
__device__ __forceinline__ void panel_store(u64* p, u64 v) {
    __hip_atomic_store(p, v, __ATOMIC_RELAXED, __HIP_MEMORY_SCOPE_AGENT);
}

// tanh on 4 packed f16 (used for the bottleneck tanh, applied on L3's ingest)
__device__ __forceinline__ u64 tanh4_f16(u64 v) {
    f16x4 h = __builtin_bit_cast(f16x4, v);
    f16x4 r;
#pragma unroll
    for (int i = 0; i < 4; ++i) r[i] = (f16)tanh_f((float)h[i]);
    return __builtin_bit_cast(u64, r);
}

// One LSTM layer over one 16-batch group, run by NT=4H threads.
// MFMA structure identical to rounds 2-4 (numerics verified, absmax 4.9e-4).
// IN_TANH applies tanh to incoming panel data (bottleneck tanh before L3) —
// the producing layer's recurrence stays un-tanh'd, as the reference requires.
template <int IN_DIM, int H, bool IN_F32, bool OUT_PANEL, bool IN_TANH>
__device__ __forceinline__ void lstm_layer_dev(
    char* sm,
    const void* __restrict__ xv,       // IN_F32 ? f32 [T,B,IN] : f16 [T,B,IN]
    const int* in_flag,                // upstream flag (unused if IN_F32)
    int* out_flag,                     // our flag (unused if !OUT_PANEL)
    const float* __restrict__ w_ih, const float* __restrict__ w_hh,
    const float* __restrict__ b_ih, const float* __restrict__ b_hh,
    void* __restrict__ outv,           // OUT_PANEL ? f16 [T,B,H] : f32 [T,B,H]
    int group, int ltid)
{
    constexpr int KTX = IN_DIM / 32, KTH = H / 32, KT = KTX + KTH;
    constexpr int XP = IN_DIM + 8, HP = H + 8, NT = 4 * H;

    f16 (*xs)[16][XP] = (f16(*)[16][XP])sm;                       // [2][16][XP]
    f16 (*hs)[16][HP] = (f16(*)[16][HP])(sm + 2 * 16 * XP * 2);   // [2][16][HP]

    const int wave = ltid >> 6, lane = ltid & 63;
    const int col = lane & 15, q = lane >> 4;
    const int bblk = group * 16;
    const int u = wave * 16 + col;

    // ---- one-time: B-fragments (weights) -> registers ----
    f16x8 bw[4][KT];
#pragma unroll
    for (int g = 0; g < 4; ++g) {
        const int row = g * H + u;
#pragma unroll
        for (int kt = 0; kt < KTX; ++kt) {
            const float* p = w_ih + (size_t)row * IN_DIM + kt * 32 + q * 8;
            f16x8 v;
#pragma unroll
            for (int j = 0; j < 8; ++j) v[j] = (f16)p[j];
            bw[g][kt] = v;
        }
#pragma unroll
        for (int kt = 0; kt < KTH; ++kt) {
            const float* p = w_hh + (size_t)row * H + kt * 32 + q * 8;
            f16x8 v;
#pragma unroll
            for (int j = 0; j < 8; ++j) v[j] = (f16)p[j];
            bw[g][KTX + kt] = v;
        }
    }
    float bias[4];
#pragma unroll
    for (int g = 0; g < 4; ++g) bias[g] = b_ih[g * H + u] + b_hh[g * H + u];
    float cst[4] = {0.f, 0.f, 0.f, 0.f};

    // ---- input staging setup: chunks of 4 elements (16B f32 / 8B f16) ----
    constexpr int EPR = IN_DIM / 4;
    constexpr int NCH = 16 * EPR;
    constexpr int CPT = (NCH + NT - 1) / NT;
    constexpr long XADVB = (long)BATCH * IN_DIM * (IN_F32 ? 4 : 2);
    bool sv[CPT]; const char* sgp[CPT]; f16* slp[CPT];
    constexpr int LDSD = 16 * XP;
#pragma unroll
    for (int k = 0; k < CPT; ++k) {
        const int cc = ltid + k * NT;
        sv[k] = (cc < NCH);
        const int r_ = (cc < NCH ? cc : 0) / EPR;
        const int o_ = (cc < NCH ? cc : 0) % EPR;
        sgp[k] = (const char*)xv + ((size_t)(bblk + r_) * IN_DIM + o_ * 4) * (IN_F32 ? 4 : 2);
        slp[k] = &xs[0][r_][o_ * 4];
    }

    // ---- output setup ----
    constexpr int OEPR = H / 4;            // u64 chunks per row; NT == 16*OEPR
    u64* opg = nullptr;
    f16* olds = nullptr;
    float* outp_f32 = nullptr;
    if constexpr (OUT_PANEL) {
        const int orow = ltid / OEPR, ooff = ltid % OEPR;
        opg  = (u64*)((f16*)outv + (size_t)(bblk + orow) * H) + ooff;
        olds = &hs[0][orow][ooff * 4];
    } else {
        outp_f32 = (float*)outv + ((size_t)bblk + 4 * q) * H + u;
    }
    constexpr int HLDSD = 16 * HP;

    // ---- pre-loop: zero h(0); wait upstream; stage x(0) ----
    for (int i = ltid; i < 16 * HP; i += NT) hs[0][i / HP][i % HP] = (f16)0.f;
    int seen = 0;
    if constexpr (!IN_F32) {
        do { seen = flag_load(in_flag); } while (seen < 1);
    }
#pragma unroll
    for (int k = 0; k < CPT; ++k) {
        if (sv[k]) {
            if constexpr (IN_F32) {
                const f32x4 v = *reinterpret_cast<const f32x4*>(sgp[k]);
                f16x4 h4;
                h4[0] = (f16)v[0]; h4[1] = (f16)v[1]; h4[2] = (f16)v[2]; h4[3] = (f16)v[3];
                *reinterpret_cast<f16x4*>(slp[k]) = h4;
            } else {
                u64 v = panel_load((const u64*)sgp[k]);
                if constexpr (IN_TANH) v = tanh4_f16(v);
                *reinterpret_cast<u64*>(slp[k]) = v;
            }
            sgp[k] += XADVB;
        }
    }
    barrier_step();

    float hold[4] = {0.f, 0.f, 0.f, 0.f};
    int pb = 0;
    for (int t = 0; t < T_STEPS + 2; ++t) {
        // signal: panels 0..t-2 were vm-drained before the previous barrier
        if constexpr (OUT_PANEL) {
            if (t >= 2 && ltid == 0) flag_store(out_flag, t - 1);
        }

        // prefetch x(t+1) (spin on upstream flag only if not already seen)
        f32x4 xr32[CPT]; u64 xr16[CPT];
        const bool pf = (t + 1 < T_STEPS);
        if (pf) {
            if constexpr (!IN_F32) {
                if (seen < t + 2) {
                    do { seen = flag_load(in_flag); } while (seen < t + 2);
                }
            }
#pragma unroll
            for (int k = 0; k < CPT; ++k) {
                if (sv[k]) {
                    if constexpr (IN_F32)
                        xr32[k] = *reinterpret_cast<const f32x4*>(sgp[k]);
                    else
                        xr16[k] = panel_load((const u64*)sgp[k]);
                    sgp[k] += XADVB;
                }
            }
        }

        // write step t-1's output (h(t-1) is in hs[pb])
        if (t >= 1 && t <= T_STEPS) {
            if constexpr (OUT_PANEL) {
                const u64 v = *reinterpret_cast<const u64*>(olds + pb * HLDSD);
                panel_store(opg, v);
                opg += (size_t)BATCH * H / 4;
            } else {
#pragma unroll
                for (int r = 0; r < 4; ++r) outp_f32[r * H] = hold[r];
                outp_f32 += (size_t)BATCH * H;
            }
        }

        if (t < T_STEPS) {
            // A-fragments
            f16x8 a[KT];
#pragma unroll
            for (int kt = 0; kt < KTX; ++kt)
                a[kt] = *reinterpret_cast<const f16x8*>(&xs[pb][col][kt * 32 + q * 8]);
#pragma unroll
            for (int kt = 0; kt < KTH; ++kt)
                a[KTX + kt] = *reinterpret_cast<const f16x8*>(&hs[pb][col][kt * 32 + q * 8]);

            // MFMA
            f32x4 acc[4];
#pragma unroll
            for (int g = 0; g < 4; ++g)
                acc[g] = (f32x4){bias[g], bias[g], bias[g], bias[g]};
#pragma unroll
            for (int kt = 0; kt < KT; ++kt)
#pragma unroll
                for (int g = 0; g < 4; ++g)
                    acc[g] = __builtin_amdgcn_mfma_f32_16x16x32_f16(a[kt], bw[g][kt], acc[g], 0, 0, 0);

            // commit x(t+1)
            if (pf) {
#pragma unroll
                for (int k = 0; k < CPT; ++k) {
                    if (sv[k]) {
                        f16* dst = slp[k] + (pb ^ 1) * LDSD;
                        if constexpr (IN_F32) {
                            f16x4 h4;
                            h4[0] = (f16)xr32[k][0]; h4[1] = (f16)xr32[k][1];
                            h4[2] = (f16)xr32[k][2]; h4[3] = (f16)xr32[k][3];
                            *reinterpret_cast<f16x4*>(dst) = h4;
                        } else {
                            u64 v = xr16[k];
                            if constexpr (IN_TANH) v = tanh4_f16(v);
                            *reinterpret_cast<u64*>(dst) = v;
                        }
                    }
                }
            }

            // gates -> c, h(t); recurrence h stored RAW (tanh only on L3 ingest)
#pragma unroll
            for (int r = 0; r < 4; ++r) {
                const float gi = acc[0][r];
                const float gf = acc[1][r];
                const float gg = acc[2][r];
                const float go = acc[3][r];
                cst[r] = sigmoid_f(gf) * cst[r] + sigmoid_f(gi) * tanh_f(gg);
                const float h = sigmoid_f(go) * tanh_f(cst[r]);
                hs[pb ^ 1][4 * q + r][u] = (f16)h;
                if constexpr (!OUT_PANEL) hold[r] = h;
            }

            // early flag refresh (hides poll latency in steady state)
            if constexpr (!IN_F32) {
                if (t + 2 < T_STEPS && seen < t + 3) seen = flag_load(in_flag);
            }
        }

        barrier_step();
        pb ^= 1;
    }
}

__global__ __launch_bounds__(512, 1)
void lstm_fused(const float* __restrict__ X,
                const float* __restrict__ w1_ih, const float* __restrict__ w1_hh,
                const float* __restrict__ b1_ih, const float* __restrict__ b1_hh,
                const float* __restrict__ w2_ih, const float* __restrict__ w2_hh,
                const float* __restrict__ b2_ih, const float* __restrict__ b2_hh,
                const float* __restrict__ w3_ih, const float* __restrict__ w3_hh,
                const float* __restrict__ b3_ih, const float* __restrict__ b3_hh,
                const float* __restrict__ w4_ih, const float* __restrict__ w4_hh,
                const float* __restrict__ b4_ih, const float* __restrict__ b4_hh,
                f16* __restrict__ h1, f16* __restrict__ h2, f16* __restrict__ h3,
                int* __restrict__ flags, float* __restrict__ out)
{
    __shared__ __attribute__((aligned(16))) char smem[45056];
    const int b = blockIdx.x, tid = threadIdx.x;

    if (b < 16) {
        // L1: 64 -> 128, fp32 in, panel out, 1 group/block (512 thr)
        lstm_layer_dev<64, 128, true, true, false>(
            smem, X, nullptr, flags + 0 * 16 + b,
            w1_ih, w1_hh, b1_ih, b1_hh, h1, b, tid);
    } else if (b < 20) {
        // L2: 128 -> 32, 4 groups/block (128 thr each); h2 = raw LSTM h
        const int gl = tid >> 7;
        const int g  = (b - 16) * 4 + gl;
        lstm_layer_dev<128, 32, false, true, false>(
            smem + gl * 11264, h1, flags + 0 * 16 + g, flags + 1 * 16 + g,
            w2_ih, w2_hh, b2_ih, b2_hh, h2, g, tid & 127);
    } else if (b < 36) {
        // L3: 32 -> 128; bottleneck tanh applied on ingest (IN_TANH)
        const int g = b - 20;
        lstm_layer_dev<32, 128, false, true, true>(
            smem, h2, flags + 1 * 16 + g, flags + 2 * 16 + g,
            w3_ih, w3_hh, b3_ih, b3_hh, h3, g, tid);
    } else {
        // L4: 128 -> 64, 2 groups/block (256 thr each), fp32 final out
        const int gl = tid >> 8;
        const int g  = (b - 36) * 2 + gl;
        lstm_layer_dev<128, 64, false, false, false>(
            smem + gl * 13312, h3, flags + 2 * 16 + g, nullptr,
            w4_ih, w4_hh, b4_ih, b4_hh, out, g, tid & 255);
    }
}

extern "C" void kernel_launch(void* const* d_in, const int* in_sizes, int n_in,
                              void* d_out, int out_size, void* d_ws, size_t ws_size,
                              hipStream_t stream) {
    const float* X     = (const float*)d_in[0];
    const float* w1_ih = (const float*)d_in[1];
    const float* w1_hh = (const float*)d_in[2];
    const float* b1_ih = (const float*)d_in[3];
    const float* b1_hh = (const float*)d_in[4];
    const float* w2_ih = (const float*)d_in[5];
    const float* w2_hh = (const float*)d_in[6];
    const float* b2_ih = (const float*)d_in[7];
    const float* b2_hh = (const float*)d_in[8];
    const float* w3_ih = (const float*)d_in[9];
    const float* w3_hh = (const float*)d_in[10];
    const float* b3_ih = (const float*)d_in[11];
    const float* b3_hh = (const float*)d_in[12];
    const float* w4_ih = (const float*)d_in[13];
    const float* w4_hh = (const float*)d_in[14];
    const float* b4_ih = (const float*)d_in[15];
    const float* b4_hh = (const float*)d_in[16];

    float* out = (float*)d_out;

    // ws: flags[48] ints (poison 0xAAAAAAAA < 0 => "not ready"), then f16
    // panels h1 [T,B,128], h2 [T,B,32], h3 [T,B,128]  (~75.5 MB total)
    int* flags = (int*)d_ws;
    f16* h1 = (f16*)((char*)d_ws + 256);
    f16* h2 = h1 + (size_t)T_STEPS * BATCH * 128;
    f16* h3 = h2 + (size_t)T_STEPS * BATCH * 32;

    lstm_fused<<<44, 512, 0, stream>>>(X,
        w1_ih, w1_hh, b1_ih, b1_hh, w2_ih, w2_hh, b2_ih, b2_hh,
        w3_ih, w3_hh, b3_ih, b3_hh, w4_ih, w4_hh, b4_ih, b4_hh,
        h1, h2, h3, flags, out);
}

// Round 6
// 760.898 us; speedup vs baseline: 3.9177x; 1.3626x over previous
//
#include <hip/hip_runtime.h>

#define T_STEPS 512
#define BATCH   256

typedef _Float16 f16;
typedef unsigned long long u64;
typedef __attribute__((ext_vector_type(8))) _Float16 f16x8;
typedef __attribute__((ext_vector_type(4))) _Float16 f16x4;
typedef __attribute__((ext_vector_type(4))) float    f32x4;

__device__ __forceinline__ float rcp_f(float x) { return __builtin_amdgcn_rcpf(x); }
__device__ __forceinline__ float sigmoid_f(float x) { return rcp_f(1.0f + __expf(-x)); }
__device__ __forceinline__ float tanh_f(float x) {
    return 1.0f - 2.0f * rcp_f(__expf(2.0f * x) + 1.0f);
}

// Per-step barrier: LDS visibility only. Global stores/loads are NOT drained
// here (that was round 5's 1000-cyc/step mistake).
__device__ __forceinline__ void barrier_lgkm() {
    asm volatile("s_waitcnt lgkmcnt(0)\n\ts_barrier" ::: "memory");
}
// Signal-point barrier: every wave drains all its VMEM (panel stores included)
// before the barrier -> after it, all panels issued earlier are globally
// visible and lane 0 may publish the flag.
__device__ __forceinline__ void barrier_drain() {
    asm volatile("s_waitcnt vmcnt(0) lgkmcnt(0)\n\ts_barrier" ::: "memory");
}

// Agent-scope relaxed atomics -> sc1 ops, coherent at the L3 across XCDs.
__device__ __forceinline__ int  flag_load(const int* p) {
    return __hip_atomic_load(p, __ATOMIC_RELAXED, __HIP_MEMORY_SCOPE_AGENT);
}
__device__ __forceinline__ void flag_store(int* p, int v) {
    __hip_atomic_store(p, v, __ATOMIC_RELAXED, __HIP_MEMORY_SCOPE_AGENT);
}
__device__ __forceinline__ u64  panel_load(const u64* p) {
    return __hip_atomic_load(p, __ATOMIC_RELAXED, __HIP_MEMORY_SCOPE_AGENT);
}
__device__ __forceinline__ void panel_store(u64* p, u64 v) {
    __hip_atomic_store(p, v, __ATOMIC_RELAXED, __HIP_MEMORY_SCOPE_AGENT);
}

// tanh on 4 packed f16 (bottleneck tanh, applied on L3's ingest)
__device__ __forceinline__ u64 tanh4_f16(u64 v) {
    f16x4 h = __builtin_bit_cast(f16x4, v);
    f16x4 r;
#pragma unroll
    for (int i = 0; i < 4; ++i) r[i] = (f16)tanh_f((float)h[i]);
    return __builtin_bit_cast(u64, r);
}

// One LSTM layer over one 16-batch group, run by NT=4H threads.
// MFMA structure verified rounds 2-5 (absmax 4.9e-4). Pipeline protocol:
// flag f means "x panels 0..f-1 are globally visible". Producer publishes
// f = t-1 at top of steps t ≡ 0 (mod 4) (after a drain barrier at end of
// t-1 ≡ 3). Consumer at step τ prefetches x(τ+1) once flag ≥ τ+2.
template <int IN_DIM, int H, bool IN_F32, bool OUT_PANEL, bool IN_TANH>
__device__ __forceinline__ void lstm_layer_dev(
    char* sm,
    const void* __restrict__ xv,       // IN_F32 ? f32 [T,B,IN] : f16 [T,B,IN]
    const int* in_flag,                // upstream flag (unused if IN_F32)
    int* out_flag,                     // our flag (unused if !OUT_PANEL)
    const float* __restrict__ w_ih, const float* __restrict__ w_hh,
    const float* __restrict__ b_ih, const float* __restrict__ b_hh,
    void* __restrict__ outv,           // OUT_PANEL ? f16 [T,B,H] : f32 [T,B,H]
    int group, int ltid)
{
    constexpr int KTX = IN_DIM / 32, KTH = H / 32, KT = KTX + KTH;
    constexpr int XP = IN_DIM + 8, HP = H + 8, NT = 4 * H;

    f16 (*xs)[16][XP] = (f16(*)[16][XP])sm;                       // [2][16][XP]
    f16 (*hs)[16][HP] = (f16(*)[16][HP])(sm + 2 * 16 * XP * 2);   // [2][16][HP]

    const int wave = ltid >> 6, lane = ltid & 63;
    const int col = lane & 15, q = lane >> 4;
    const int bblk = group * 16;
    const int u = wave * 16 + col;

    // ---- one-time: B-fragments (weights) -> registers ----
    f16x8 bw[4][KT];
#pragma unroll
    for (int g = 0; g < 4; ++g) {
        const int row = g * H + u;
#pragma unroll
        for (int kt = 0; kt < KTX; ++kt) {
            const float* p = w_ih + (size_t)row * IN_DIM + kt * 32 + q * 8;
            f16x8 v;
#pragma unroll
            for (int j = 0; j < 8; ++j) v[j] = (f16)p[j];
            bw[g][kt] = v;
        }
#pragma unroll
        for (int kt = 0; kt < KTH; ++kt) {
            const float* p = w_hh + (size_t)row * H + kt * 32 + q * 8;
            f16x8 v;
#pragma unroll
            for (int j = 0; j < 8; ++j) v[j] = (f16)p[j];
            bw[g][KTX + kt] = v;
        }
    }
    float bias[4];
#pragma unroll
    for (int g = 0; g < 4; ++g) bias[g] = b_ih[g * H + u] + b_hh[g * H + u];
    float cst[4] = {0.f, 0.f, 0.f, 0.f};

    // ---- input staging setup: chunks of 4 elements (16B f32 / 8B f16) ----
    constexpr int EPR = IN_DIM / 4;
    constexpr int NCH = 16 * EPR;
    constexpr int CPT = (NCH + NT - 1) / NT;
    constexpr long XADVB = (long)BATCH * IN_DIM * (IN_F32 ? 4 : 2);
    bool sv[CPT]; const char* sgp[CPT]; f16* slp[CPT];
    constexpr int LDSD = 16 * XP;
#pragma unroll
    for (int k = 0; k < CPT; ++k) {
        const int cc = ltid + k * NT;
        sv[k] = (cc < NCH);
        const int r_ = (cc < NCH ? cc : 0) / EPR;
        const int o_ = (cc < NCH ? cc : 0) % EPR;
        sgp[k] = (const char*)xv + ((size_t)(bblk + r_) * IN_DIM + o_ * 4) * (IN_F32 ? 4 : 2);
        slp[k] = &xs[0][r_][o_ * 4];
    }

    // ---- output setup ----
    constexpr int OEPR = H / 4;            // u64 chunks per row; NT == 16*OEPR
    u64* opg = nullptr;
    f16* olds = nullptr;
    float* outp_f32 = nullptr;
    if constexpr (OUT_PANEL) {
        const int orow = ltid / OEPR, ooff = ltid % OEPR;
        opg  = (u64*)((f16*)outv + (size_t)(bblk + orow) * H) + ooff;
        olds = &hs[0][orow][ooff * 4];
    } else {
        outp_f32 = (float*)outv + ((size_t)bblk + 4 * q) * H + u;
    }
    constexpr int HLDSD = 16 * HP;

    // ---- pre-loop: zero h(0); wait upstream; stage x(0) ----
    for (int i = ltid; i < 16 * HP; i += NT) hs[0][i / HP][i % HP] = (f16)0.f;
    int seen = 0;
    if constexpr (!IN_F32) {
        do { seen = flag_load(in_flag); } while (seen < 1);
    }
#pragma unroll
    for (int k = 0; k < CPT; ++k) {
        if (sv[k]) {
            if constexpr (IN_F32) {
                const f32x4 v = *reinterpret_cast<const f32x4*>(sgp[k]);
                f16x4 h4;
                h4[0] = (f16)v[0]; h4[1] = (f16)v[1]; h4[2] = (f16)v[2]; h4[3] = (f16)v[3];
                *reinterpret_cast<f16x4*>(slp[k]) = h4;
            } else {
                u64 v = panel_load((const u64*)sgp[k]);
                if constexpr (IN_TANH) v = tanh4_f16(v);
                *reinterpret_cast<u64*>(slp[k]) = v;
            }
            sgp[k] += XADVB;
        }
    }
    barrier_drain();

    float hold[4] = {0.f, 0.f, 0.f, 0.f};
    int pb = 0;
    for (int t = 0; t < T_STEPS; ++t) {
        // publish flag at 4-step boundaries (previous barrier was a drain)
        if constexpr (OUT_PANEL) {
            if ((t & 3) == 0 && t >= 4 && ltid == 0) flag_store(out_flag, t - 1);
        }

        // prefetch x(t+1): spin only if not already seen
        f32x4 xr32[CPT]; u64 xr16[CPT];
        const bool pf = (t + 1 < T_STEPS);
        if (pf) {
            if constexpr (!IN_F32) {
                if (seen < t + 2) {
                    do { seen = flag_load(in_flag); } while (seen < t + 2);
                }
            }
#pragma unroll
            for (int k = 0; k < CPT; ++k) {
                if (sv[k]) {
                    if constexpr (IN_F32)
                        xr32[k] = *reinterpret_cast<const f32x4*>(sgp[k]);
                    else
                        xr16[k] = panel_load((const u64*)sgp[k]);
                    sgp[k] += XADVB;
                }
            }
        }

        // write step t-1's output (h(t-1) sits in hs[pb])
        if (t >= 1) {
            if constexpr (OUT_PANEL) {
                const u64 v = *reinterpret_cast<const u64*>(olds + pb * HLDSD);
                panel_store(opg, v);
                opg += (size_t)BATCH * H / 4;
            } else {
#pragma unroll
                for (int r = 0; r < 4; ++r) outp_f32[r * H] = hold[r];
                outp_f32 += (size_t)BATCH * H;
            }
        }

        // A-fragments
        f16x8 a[KT];
#pragma unroll
        for (int kt = 0; kt < KTX; ++kt)
            a[kt] = *reinterpret_cast<const f16x8*>(&xs[pb][col][kt * 32 + q * 8]);
#pragma unroll
        for (int kt = 0; kt < KTH; ++kt)
            a[KTX + kt] = *reinterpret_cast<const f16x8*>(&hs[pb][col][kt * 32 + q * 8]);

        // MFMA
        f32x4 acc[4];
#pragma unroll
        for (int g = 0; g < 4; ++g)
            acc[g] = (f32x4){bias[g], bias[g], bias[g], bias[g]};
#pragma unroll
        for (int kt = 0; kt < KT; ++kt)
#pragma unroll
            for (int g = 0; g < 4; ++g)
                acc[g] = __builtin_amdgcn_mfma_f32_16x16x32_f16(a[kt], bw[g][kt], acc[g], 0, 0, 0);

        // gates -> c, h(t); recurrence h stored RAW (tanh only on L3 ingest)
#pragma unroll
        for (int r = 0; r < 4; ++r) {
            const float gi = acc[0][r];
            const float gf = acc[1][r];
            const float gg = acc[2][r];
            const float go = acc[3][r];
            cst[r] = sigmoid_f(gf) * cst[r] + sigmoid_f(gi) * tanh_f(gg);
            const float h = sigmoid_f(go) * tanh_f(cst[r]);
            hs[pb ^ 1][4 * q + r][u] = (f16)h;
            if constexpr (!OUT_PANEL) hold[r] = h;
        }

        // commit x(t+1) LAST: maximizes latency hiding for the sc1 loads
        if (pf) {
#pragma unroll
            for (int k = 0; k < CPT; ++k) {
                if (sv[k]) {
                    f16* dst = slp[k] + (pb ^ 1) * LDSD;
                    if constexpr (IN_F32) {
                        f16x4 h4;
                        h4[0] = (f16)xr32[k][0]; h4[1] = (f16)xr32[k][1];
                        h4[2] = (f16)xr32[k][2]; h4[3] = (f16)xr32[k][3];
                        *reinterpret_cast<f16x4*>(dst) = h4;
                    } else {
                        u64 v = xr16[k];
                        if constexpr (IN_TANH) v = tanh4_f16(v);
                        *reinterpret_cast<u64*>(dst) = v;
                    }
                }
            }
        }

        // early flag refresh (keeps steady-state spins rare)
        if constexpr (!IN_F32) {
            if (seen < t + 8) seen = flag_load(in_flag);
        }

        if ((t & 3) == 3) barrier_drain(); else barrier_lgkm();
        pb ^= 1;
    }

    // ---- epilogue: final output (h(T-1) in hs[pb]), drain, final flag ----
    if constexpr (OUT_PANEL) {
        const u64 v = *reinterpret_cast<const u64*>(olds + pb * HLDSD);
        panel_store(opg, v);
    } else {
#pragma unroll
        for (int r = 0; r < 4; ++r) outp_f32[r * H] = hold[r];
    }
    barrier_drain();
    if constexpr (OUT_PANEL) {
        if (ltid == 0) flag_store(out_flag, T_STEPS + 4);
    }
}

__global__ __launch_bounds__(512, 1)
void lstm_fused(const float* __restrict__ X,
                const float* __restrict__ w1_ih, const float* __restrict__ w1_hh,
                const float* __restrict__ b1_ih, const float* __restrict__ b1_hh,
                const float* __restrict__ w2_ih, const float* __restrict__ w2_hh,
                const float* __restrict__ b2_ih, const float* __restrict__ b2_hh,
                const float* __restrict__ w3_ih, const float* __restrict__ w3_hh,
                const float* __restrict__ b3_ih, const float* __restrict__ b3_hh,
                const float* __restrict__ w4_ih, const float* __restrict__ w4_hh,
                const float* __restrict__ b4_ih, const float* __restrict__ b4_hh,
                f16* __restrict__ h1, f16* __restrict__ h2, f16* __restrict__ h3,
                int* __restrict__ flags, float* __restrict__ out)
{
    __shared__ __attribute__((aligned(16))) char smem[45056];
    const int b = blockIdx.x, tid = threadIdx.x;

    if (b < 16) {
        // L1: 64 -> 128, fp32 in, panel out, 1 group/block (512 thr)
        lstm_layer_dev<64, 128, true, true, false>(
            smem, X, nullptr, flags + 0 * 16 + b,
            w1_ih, w1_hh, b1_ih, b1_hh, h1, b, tid);
    } else if (b < 20) {
        // L2: 128 -> 32, 4 groups/block (128 thr each); h2 = raw LSTM h
        const int gl = tid >> 7;
        const int g  = (b - 16) * 4 + gl;
        lstm_layer_dev<128, 32, false, true, false>(
            smem + gl * 11264, h1, flags + 0 * 16 + g, flags + 1 * 16 + g,
            w2_ih, w2_hh, b2_ih, b2_hh, h2, g, tid & 127);
    } else if (b < 36) {
        // L3: 32 -> 128; bottleneck tanh applied on ingest (IN_TANH)
        const int g = b - 20;
        lstm_layer_dev<32, 128, false, true, true>(
            smem, h2, flags + 1 * 16 + g, flags + 2 * 16 + g,
            w3_ih, w3_hh, b3_ih, b3_hh, h3, g, tid);
    } else {
        // L4: 128 -> 64, 2 groups/block (256 thr each), fp32 final out
        const int gl = tid >> 8;
        const int g  = (b - 36) * 2 + gl;
        lstm_layer_dev<128, 64, false, false, false>(
            smem + gl * 13312, h3, flags + 2 * 16 + g, nullptr,
            w4_ih, w4_hh, b4_ih, b4_hh, out, g, tid & 255);
    }
}

extern "C" void kernel_launch(void* const* d_in, const int* in_sizes, int n_in,
                              void* d_out, int out_size, void* d_ws, size_t ws_size,
                              hipStream_t stream) {
    const float* X     = (const float*)d_in[0];
    const float* w1_ih = (const float*)d_in[1];
    const float* w1_hh = (const float*)d_in[2];
    const float* b1_ih = (const float*)d_in[3];
    const float* b1_hh = (const float*)d_in[4];
    const float* w2_ih = (const float*)d_in[5];
    const float* w2_hh = (const float*)d_in[6];
    const float* b2_ih = (const float*)d_in[7];
    const float* b2_hh = (const float*)d_in[8];
    const float* w3_ih = (const float*)d_in[9];
    const float* w3_hh = (const float*)d_in[10];
    const float* b3_ih = (const float*)d_in[11];
    const float* b3_hh = (const float*)d_in[12];
    const float* w4_ih = (const float*)d_in[13];
    const float* w4_hh = (const float*)d_in[14];
    const float* b4_ih = (const float*)d_in[15];
    const float* b4_hh = (const float*)d_in[16];

    float* out = (float*)d_out;

    // ws: flags[48] ints (poison 0xAAAAAAAA < 0 => "not ready"), then f16
    // panels h1 [T,B,128], h2 [T,B,32], h3 [T,B,128]  (~75.5 MB total)
    int* flags = (int*)d_ws;
    f16* h1 = (f16*)((char*)d_ws + 256);
    f16* h2 = h1 + (size_t)T_STEPS * BATCH * 128;
    f16* h3 = h2 + (size_t)T_STEPS * BATCH * 32;

    lstm_fused<<<44, 512, 0, stream>>>(X,
        w1_ih, w1_hh, b1_ih, b1_hh, w2_ih, w2_hh, b2_ih, b2_hh,
        w3_ih, w3_hh, b3_ih, b3_hh, w4_ih, w4_hh, b4_ih, b4_hh,
        h1, h2, h3, flags, out);
}

// Round 7
// 649.392 us; speedup vs baseline: 4.5904x; 1.1717x over previous
//
#include <hip/hip_runtime.h>

#define T_STEPS 512
#define BATCH   256

typedef _Float16 f16;
typedef unsigned long long u64;
typedef __attribute__((ext_vector_type(8))) _Float16 f16x8;
typedef __attribute__((ext_vector_type(4))) _Float16 f16x4;
typedef __attribute__((ext_vector_type(4))) float    f32x4;

#define L2E 1.44269504088896340736f

__device__ __forceinline__ float rcp_f(float x)  { return __builtin_amdgcn_rcpf(x); }
__device__ __forceinline__ float exp2_f(float x) { return __builtin_amdgcn_exp2f(x); }

// tanh in exp2 domain: tanh(x) = 1 - 2/(exp2(2*log2e*x)+1)
__device__ __forceinline__ float tanh_n(float x) {
    return fmaf(-2.0f, rcp_f(1.0f + exp2_f(2.0f * L2E * x)), 1.0f);
}
// tanh on 4 packed f16 (bottleneck tanh, applied on L2's panel store)
__device__ __forceinline__ u64 tanh4_f16(u64 v) {
    f16x4 h = __builtin_bit_cast(f16x4, v);
    f16x4 r;
#pragma unroll
    for (int i = 0; i < 4; ++i) r[i] = (f16)tanh_n((float)h[i]);
    return __builtin_bit_cast(u64, r);
}

// Per-step barrier: LDS visibility only (global ops NOT drained).
__device__ __forceinline__ void barrier_lgkm() {
    asm volatile("s_waitcnt lgkmcnt(0)\n\ts_barrier" ::: "memory");
}
// Signal-point barrier: drain all VMEM so panels are globally visible.
__device__ __forceinline__ void barrier_drain() {
    asm volatile("s_waitcnt vmcnt(0) lgkmcnt(0)\n\ts_barrier" ::: "memory");
}

// Agent-scope relaxed atomics -> sc1 ops, coherent at L3 across XCDs.
__device__ __forceinline__ int  flag_load(const int* p) {
    return __hip_atomic_load(p, __ATOMIC_RELAXED, __HIP_MEMORY_SCOPE_AGENT);
}
__device__ __forceinline__ void flag_store(int* p, int v) {
    __hip_atomic_store(p, v, __ATOMIC_RELAXED, __HIP_MEMORY_SCOPE_AGENT);
}
__device__ __forceinline__ u64  panel_load(const u64* p) {
    return __hip_atomic_load(p, __ATOMIC_RELAXED, __HIP_MEMORY_SCOPE_AGENT);
}
__device__ __forceinline__ void panel_store(u64* p, u64 v) {
    __hip_atomic_store(p, v, __ATOMIC_RELAXED, __HIP_MEMORY_SCOPE_AGENT);
}

// One LSTM layer over one 16-batch group (NT = 4H threads). MFMA structure
// verified rounds 2-6. Weights/biases are scaled by log2e (gates i,f,o) and
// 2*log2e (gate g) at load time; cell state kept in the 2*log2e domain so all
// nonlinearities are rcp(1+exp2(+/-y)) with no runtime multiplies.
// Pipeline: flag f = "x panels 0..f-1 globally visible"; producer publishes
// f = t-1 at steps t%4==0 (after drain barrier at end of t-1); consumer at
// step tau prefetches x(tau+1) once flag >= tau+2.
template <int IN_DIM, int H, bool IN_F32, bool OUT_PANEL, bool OUT_TANH>
__device__ __forceinline__ void lstm_layer_dev(
    char* sm,
    const void* __restrict__ xv,       // IN_F32 ? f32 [T,B,IN] : f16 [T,B,IN]
    const int* in_flag,                // upstream flag (unused if IN_F32)
    int* out_flag,                     // our flag (unused if !OUT_PANEL)
    const float* __restrict__ w_ih, const float* __restrict__ w_hh,
    const float* __restrict__ b_ih, const float* __restrict__ b_hh,
    void* __restrict__ outv,           // OUT_PANEL ? f16 [T,B,H] : f32 [T,B,H]
    int group, int ltid)
{
    constexpr int KTX = IN_DIM / 32, KTH = H / 32, KT = KTX + KTH;
    constexpr int XP = IN_DIM + 8, HP = H + 8, NT = 4 * H;

    f16 (*xs)[16][XP] = (f16(*)[16][XP])sm;                       // [2][16][XP]
    f16 (*hs)[16][HP] = (f16(*)[16][HP])(sm + 2 * 16 * XP * 2);   // [2][16][HP]

    const int wave = ltid >> 6, lane = ltid & 63;
    const int col = lane & 15, q = lane >> 4;
    const int bblk = group * 16;
    const int u = wave * 16 + col;

    // ---- one-time: B-fragments (weights, log2e-scaled) -> registers ----
    f16x8 bw[4][KT];
#pragma unroll
    for (int g = 0; g < 4; ++g) {
        const float sc = (g == 2) ? 2.0f * L2E : L2E;
        const int row = g * H + u;
#pragma unroll
        for (int kt = 0; kt < KTX; ++kt) {
            const float* p = w_ih + (size_t)row * IN_DIM + kt * 32 + q * 8;
            f16x8 v;
#pragma unroll
            for (int j = 0; j < 8; ++j) v[j] = (f16)(p[j] * sc);
            bw[g][kt] = v;
        }
#pragma unroll
        for (int kt = 0; kt < KTH; ++kt) {
            const float* p = w_hh + (size_t)row * H + kt * 32 + q * 8;
            f16x8 v;
#pragma unroll
            for (int j = 0; j < 8; ++j) v[j] = (f16)(p[j] * sc);
            bw[g][KTX + kt] = v;
        }
    }
    float bias[4];
#pragma unroll
    for (int g = 0; g < 4; ++g)
        bias[g] = (b_ih[g * H + u] + b_hh[g * H + u]) * ((g == 2) ? 2.0f * L2E : L2E);
    float cst[4] = {0.f, 0.f, 0.f, 0.f};   // cell state, 2*log2e domain

    // ---- input staging: 16B chunks (4 f32 or 8 f16) ----
    constexpr int ELD = IN_F32 ? 4 : 8;
    constexpr int EPR = IN_DIM / ELD;
    constexpr int NCH = 16 * EPR;
    constexpr int CPT = (NCH + NT - 1) / NT;
    constexpr long XADVB = (long)BATCH * IN_DIM * (IN_F32 ? 4 : 2);
    bool sv[CPT]; const char* sgp[CPT]; f16* slp[CPT];
    constexpr int LDSD = 16 * XP;          // f16 elems between xs buffers
#pragma unroll
    for (int k = 0; k < CPT; ++k) {
        const int cc = ltid + k * NT;
        sv[k] = (cc < NCH);
        const int r_ = (cc < NCH ? cc : 0) / EPR;
        const int o_ = (cc < NCH ? cc : 0) % EPR;
        sgp[k] = (const char*)xv + ((size_t)(bblk + r_) * IN_DIM + o_ * ELD) * (IN_F32 ? 4 : 2);
        slp[k] = &xs[0][r_][o_ * ELD];
    }

    // ---- output setup ----
    constexpr int OEPR = H / 4;            // u64 chunks per row; NT == 16*OEPR
    u64* opg = nullptr;
    f16* olds = nullptr;
    float* outp_f32 = nullptr;
    if constexpr (OUT_PANEL) {
        const int orow = ltid / OEPR, ooff = ltid % OEPR;
        opg  = (u64*)((f16*)outv + (size_t)(bblk + orow) * H) + ooff;
        olds = &hs[0][orow][ooff * 4];
    } else {
        outp_f32 = (float*)outv + ((size_t)bblk + 4 * q) * H + u;
    }
    constexpr int HLDSD = 16 * HP;

    // ---- pre-loop: zero h(0); wait upstream; stage x(0) ----
    for (int i = ltid; i < 16 * HP; i += NT) hs[0][i / HP][i % HP] = (f16)0.f;
    int seen = 0;
    if constexpr (!IN_F32) {
        do { seen = flag_load(in_flag); } while (seen < 1);
    }
#pragma unroll
    for (int k = 0; k < CPT; ++k) {
        if (sv[k]) {
            if constexpr (IN_F32) {
                const f32x4 v = *reinterpret_cast<const f32x4*>(sgp[k]);
                f16x4 h4;
                h4[0] = (f16)v[0]; h4[1] = (f16)v[1]; h4[2] = (f16)v[2]; h4[3] = (f16)v[3];
                *reinterpret_cast<f16x4*>(slp[k]) = h4;
            } else {
                u64 a = panel_load((const u64*)sgp[k]);
                u64 b = panel_load((const u64*)sgp[k] + 1);
                u64 pk[2] = {a, b};
                *reinterpret_cast<f16x8*>(slp[k]) = *reinterpret_cast<const f16x8*>(pk);
            }
            sgp[k] += XADVB;
        }
    }
    barrier_drain();

    float hold[4] = {0.f, 0.f, 0.f, 0.f};

    // ---- one step; pbv/dodrain/dopub are literal at each call site ----
    auto step = [&](int t, int pbv, bool dodrain, bool dopub) {
        if constexpr (OUT_PANEL) {
            if (dopub && t >= 4 && ltid == 0) flag_store(out_flag, t - 1);
        }

        // prefetch x(t+1)
        f32x4 xr32[CPT]; u64 xr16[CPT][2];
        const bool pf = (t + 1 < T_STEPS);
        if (pf) {
            if constexpr (!IN_F32) {
                if (seen < t + 2) {
                    do { seen = flag_load(in_flag); } while (seen < t + 2);
                }
            }
#pragma unroll
            for (int k = 0; k < CPT; ++k) {
                if (sv[k]) {
                    if constexpr (IN_F32) {
                        xr32[k] = *reinterpret_cast<const f32x4*>(sgp[k]);
                    } else {
                        xr16[k][0] = panel_load((const u64*)sgp[k]);
                        xr16[k][1] = panel_load((const u64*)sgp[k] + 1);
                    }
                    sgp[k] += XADVB;
                }
            }
        }

        // write step t-1's output (h(t-1) sits in hs[pbv])
        if (t >= 1) {
            if constexpr (OUT_PANEL) {
                u64 v = *reinterpret_cast<const u64*>(olds + pbv * HLDSD);
                if constexpr (OUT_TANH) v = tanh4_f16(v);
                panel_store(opg, v);
                opg += (size_t)BATCH * H / 4;
            } else {
#pragma unroll
                for (int r = 0; r < 4; ++r) outp_f32[r * H] = hold[r];
                outp_f32 += (size_t)BATCH * H;
            }
        }

        // A-fragments
        f16x8 a[KT];
#pragma unroll
        for (int kt = 0; kt < KTX; ++kt)
            a[kt] = *reinterpret_cast<const f16x8*>(&xs[pbv][col][kt * 32 + q * 8]);
#pragma unroll
        for (int kt = 0; kt < KTH; ++kt)
            a[KTX + kt] = *reinterpret_cast<const f16x8*>(&hs[pbv][col][kt * 32 + q * 8]);

        // MFMA (accumulators bias-initialized in scaled domain)
        f32x4 acc[4];
#pragma unroll
        for (int g = 0; g < 4; ++g)
            acc[g] = (f32x4){bias[g], bias[g], bias[g], bias[g]};
#pragma unroll
        for (int kt = 0; kt < KT; ++kt)
#pragma unroll
            for (int g = 0; g < 4; ++g)
                acc[g] = __builtin_amdgcn_mfma_f32_16x16x32_f16(a[kt], bw[g][kt], acc[g], 0, 0, 0);

        // gates (exp2 domain): sigma(x)=rcp(1+exp2(-y)); tanh via rcp(1+exp2(y2))
#pragma unroll
        for (int r = 0; r < 4; ++r) {
            const float yi = acc[0][r];
            const float yf = acc[1][r];
            const float yg = acc[2][r];   // scaled by 2*log2e
            const float yo = acc[3][r];
            const float si = rcp_f(1.0f + exp2_f(-yi));
            const float sf = rcp_f(1.0f + exp2_f(-yf));
            const float dg = rcp_f(1.0f + exp2_f(yg));            // 1/(e^{2g}+1)
            const float tgp = fmaf(dg, -4.0f * L2E, 2.0f * L2E);  // 2*log2e*tanh(g)
            cst[r] = fmaf(sf, cst[r], si * tgp);                  // c' = 2*log2e*c
            const float dc = rcp_f(1.0f + exp2_f(cst[r]));
            const float th = fmaf(-2.0f, dc, 1.0f);               // tanh(c)
            const float so = rcp_f(1.0f + exp2_f(-yo));
            const float h = so * th;
            hs[pbv ^ 1][4 * q + r][u] = (f16)h;
            if constexpr (!OUT_PANEL) hold[r] = h;
        }

        // commit x(t+1) LAST (hides sc1 load latency under the step)
        if (pf) {
#pragma unroll
            for (int k = 0; k < CPT; ++k) {
                if (sv[k]) {
                    f16* dst = slp[k] + (pbv ^ 1) * LDSD;
                    if constexpr (IN_F32) {
                        f16x4 h4;
                        h4[0] = (f16)xr32[k][0]; h4[1] = (f16)xr32[k][1];
                        h4[2] = (f16)xr32[k][2]; h4[3] = (f16)xr32[k][3];
                        *reinterpret_cast<f16x4*>(dst) = h4;
                    } else {
                        *reinterpret_cast<f16x8*>(dst) =
                            *reinterpret_cast<const f16x8*>(xr16[k]);
                    }
                }
            }
        }

        // refresh 'seen' only on publish-cadence steps
        if constexpr (!IN_F32) {
            if (dopub && seen < t + 9) seen = flag_load(in_flag);
        }

        if (dodrain) barrier_drain(); else barrier_lgkm();
    };

    for (int tb = 0; tb < T_STEPS; tb += 4) {
        step(tb + 0, 0, false, true);
        step(tb + 1, 1, false, false);
        step(tb + 2, 0, false, false);
        step(tb + 3, 1, true,  false);
    }

    // ---- epilogue: final output (h(T-1) in hs[0]), drain, final flag ----
    if constexpr (OUT_PANEL) {
        u64 v = *reinterpret_cast<const u64*>(olds);
        if constexpr (OUT_TANH) v = tanh4_f16(v);
        panel_store(opg, v);
    } else {
#pragma unroll
        for (int r = 0; r < 4; ++r) outp_f32[r * H] = hold[r];
    }
    barrier_drain();
    if constexpr (OUT_PANEL) {
        if (ltid == 0) flag_store(out_flag, T_STEPS + 4);
    }
}

__global__ __launch_bounds__(512, 1)
void lstm_fused(const float* __restrict__ X,
                const float* __restrict__ w1_ih, const float* __restrict__ w1_hh,
                const float* __restrict__ b1_ih, const float* __restrict__ b1_hh,
                const float* __restrict__ w2_ih, const float* __restrict__ w2_hh,
                const float* __restrict__ b2_ih, const float* __restrict__ b2_hh,
                const float* __restrict__ w3_ih, const float* __restrict__ w3_hh,
                const float* __restrict__ b3_ih, const float* __restrict__ b3_hh,
                const float* __restrict__ w4_ih, const float* __restrict__ w4_hh,
                const float* __restrict__ b4_ih, const float* __restrict__ b4_hh,
                f16* __restrict__ h1, f16* __restrict__ h2, f16* __restrict__ h3,
                int* __restrict__ flags, float* __restrict__ out)
{
    __shared__ __attribute__((aligned(16))) char smem[45056];
    const int b = blockIdx.x, tid = threadIdx.x;

    if (b < 16) {
        // L1: 64 -> 128, fp32 in, panel out, 1 group/block (512 thr)
        lstm_layer_dev<64, 128, true, true, false>(
            smem, X, nullptr, flags + 0 * 16 + b,
            w1_ih, w1_hh, b1_ih, b1_hh, h1, b, tid);
    } else if (b < 20) {
        // L2: 128 -> 32, 4 groups/block (128 thr each); bottleneck tanh is
        // applied on the PANEL path only (recurrence h stays raw)
        const int gl = tid >> 7;
        const int g  = (b - 16) * 4 + gl;
        lstm_layer_dev<128, 32, false, true, true>(
            smem + gl * 11264, h1, flags + 0 * 16 + g, flags + 1 * 16 + g,
            w2_ih, w2_hh, b2_ih, b2_hh, h2, g, tid & 127);
    } else if (b < 36) {
        // L3: 32 -> 128; input panel h2 is already tanh'd
        const int g = b - 20;
        lstm_layer_dev<32, 128, false, true, false>(
            smem, h2, flags + 1 * 16 + g, flags + 2 * 16 + g,
            w3_ih, w3_hh, b3_ih, b3_hh, h3, g, tid);
    } else {
        // L4: 128 -> 64, 2 groups/block (256 thr each), fp32 final out
        const int gl = tid >> 8;
        const int g  = (b - 36) * 2 + gl;
        lstm_layer_dev<128, 64, false, false, false>(
            smem + gl * 13312, h3, flags + 2 * 16 + g, nullptr,
            w4_ih, w4_hh, b4_ih, b4_hh, out, g, tid & 255);
    }
}

extern "C" void kernel_launch(void* const* d_in, const int* in_sizes, int n_in,
                              void* d_out, int out_size, void* d_ws, size_t ws_size,
                              hipStream_t stream) {
    const float* X     = (const float*)d_in[0];
    const float* w1_ih = (const float*)d_in[1];
    const float* w1_hh = (const float*)d_in[2];
    const float* b1_ih = (const float*)d_in[3];
    const float* b1_hh = (const float*)d_in[4];
    const float* w2_ih = (const float*)d_in[5];
    const float* w2_hh = (const float*)d_in[6];
    const float* b2_ih = (const float*)d_in[7];
    const float* b2_hh = (const float*)d_in[8];
    const float* w3_ih = (const float*)d_in[9];
    const float* w3_hh = (const float*)d_in[10];
    const float* b3_ih = (const float*)d_in[11];
    const float* b3_hh = (const float*)d_in[12];
    const float* w4_ih = (const float*)d_in[13];
    const float* w4_hh = (const float*)d_in[14];
    const float* b4_ih = (const float*)d_in[15];
    const float* b4_hh = (const float*)d_in[16];

    float* out = (float*)d_out;

    // ws: flags[48] ints (poison 0xAAAAAAAA < 0 => "not ready"), then f16
    // panels h1 [T,B,128], h2 [T,B,32], h3 [T,B,128]
    int* flags = (int*)d_ws;
    f16* h1 = (f16*)((char*)d_ws + 256);
    f16* h2 = h1 + (size_t)T_STEPS * BATCH * 128;
    f16* h3 = h2 + (size_t)T_STEPS * BATCH * 32;

    lstm_fused<<<44, 512, 0, stream>>>(X,
        w1_ih, w1_hh, b1_ih, b1_hh, w2_ih, w2_hh, b2_ih, b2_hh,
        w3_ih, w3_hh, b3_ih, b3_hh, w4_ih, w4_hh, b4_ih, b4_hh,
        h1, h2, h3, flags, out);
}